// Round 1
// baseline (4267.335 us; speedup 1.0000x reference)
//
#include <hip/hip_runtime.h>

#define N_NODES 100000
#define E_EDGES 1600000
#define CIN 64
#define CHID 128
#define COUT 64

// ---------------- Stage A: edge pass (softmax-aggregation numer/denom) -------
// aggr = sum(msg*exp(msg)) / (sum(exp(msg)) + 1e-16)  -- max-subtraction-free,
// mathematically identical to the reference (exp(max) cancels; msg in [1e-7,~9]).
__global__ void edge_pass(const float* __restrict__ x, const int* __restrict__ ei,
                          const float* __restrict__ ea,
                          float* __restrict__ num, float* __restrict__ den) {
    long gid = (long)blockIdx.x * blockDim.x + threadIdx.x;
    int e = (int)(gid >> 4);
    int c = (int)(gid & 15) << 2;
    if (e >= E_EDGES) return;
    int src = ei[e];
    int dst = ei[E_EDGES + e];
    float4 xv = *reinterpret_cast<const float4*>(x + (long)src * CIN + c);
    float4 av = *reinterpret_cast<const float4*>(ea + (long)e * CIN + c);
    float m0 = fmaxf(xv.x + av.x, 0.f) + 1e-7f;
    float m1 = fmaxf(xv.y + av.y, 0.f) + 1e-7f;
    float m2 = fmaxf(xv.z + av.z, 0.f) + 1e-7f;
    float m3 = fmaxf(xv.w + av.w, 0.f) + 1e-7f;
    float e0 = __expf(m0), e1 = __expf(m1), e2 = __expf(m2), e3 = __expf(m3);
    float* dp = den + (long)dst * CIN + c;
    float* np = num + (long)dst * CIN + c;
    atomicAdd(dp + 0, e0);
    atomicAdd(dp + 1, e1);
    atomicAdd(dp + 2, e2);
    atomicAdd(dp + 3, e3);
    atomicAdd(np + 0, m0 * e0);
    atomicAdd(np + 1, m1 * e1);
    atomicAdd(np + 2, m2 * e2);
    atomicAdd(np + 3, m3 * e3);
}

// ---------------- h0 = num/(den+1e-16) + x  (in-place into num buffer) ------
__global__ void combine_kernel(float* __restrict__ numh0, const float* __restrict__ den,
                               const float* __restrict__ x) {
    long i = ((long)blockIdx.x * blockDim.x + threadIdx.x) * 4;
    float4 nv = *reinterpret_cast<const float4*>(numh0 + i);
    float4 dv = *reinterpret_cast<const float4*>(den + i);
    float4 xv = *reinterpret_cast<const float4*>(x + i);
    float4 h;
    h.x = nv.x / (dv.x + 1e-16f) + xv.x;
    h.y = nv.y / (dv.y + 1e-16f) + xv.y;
    h.z = nv.z / (dv.z + 1e-16f) + xv.z;
    h.w = nv.w / (dv.w + 1e-16f) + xv.w;
    *reinterpret_cast<float4*>(numh0 + i) = h;
}

// ---------------- GEMM1: t1 = h0 @ W1 + b1, accumulate BN1 sums -------------
__global__ void __launch_bounds__(256) gemm1_kernel(
        const float* __restrict__ h0, const float* __restrict__ W1,
        const float* __restrict__ b1, float* __restrict__ t1,
        float* __restrict__ stats) {
    __shared__ float sW[CIN * CHID];  // 32 KiB
    __shared__ float sh[16][CIN];     // 4 KiB
    int tid = threadIdx.x;
    for (int i = tid; i < CIN * CHID; i += 256) sW[i] = W1[i];
    int nbase = blockIdx.x * 16;
    for (int i = tid; i < 16 * CIN; i += 256) {
        int nl = i >> 6;
        sh[nl][i & 63] = h0[(long)(nbase + nl) * CIN + (i & 63)];
    }
    __syncthreads();
    int j = tid & (CHID - 1);
    int nslot = tid >> 7;  // 2 nodes per 256-thread slab
    float bb = b1[j];
    float s1 = 0.f, s2 = 0.f;
    for (int it = 0; it < 8; ++it) {
        int nl = (it << 1) + nslot;
        float acc = bb;
#pragma unroll
        for (int k = 0; k < CIN; ++k) acc = fmaf(sh[nl][k], sW[k * CHID + j], acc);
        t1[(long)(nbase + nl) * CHID + j] = acc;
        s1 += acc;
        s2 += acc * acc;
    }
    atomicAdd(&stats[j], s1);
    atomicAdd(&stats[CHID + j], s2);
}

// ---------------- finalize BN stats: mean, rsqrt(var+eps) -------------------
__global__ void finalize_kernel(const float* __restrict__ raw, float* __restrict__ mr,
                                int C, float invN) {
    int j = threadIdx.x;
    if (j < C) {
        float m = raw[j] * invN;
        float v = raw[C + j] * invN - m * m;
        mr[j] = m;
        mr[C + j] = rsqrtf(fmaxf(v, 0.f) + 1e-5f);
    }
}

// ---------------- GEMM2: h2 = relu(BN1(t1)) @ W2 + b2, BN2 sums -------------
__global__ void __launch_bounds__(256) gemm2_kernel(
        const float* __restrict__ t1, const float* __restrict__ mr1,
        const float* __restrict__ g, const float* __restrict__ be,
        const float* __restrict__ W2, const float* __restrict__ b2,
        float* __restrict__ h2, float* __restrict__ stats) {
    __shared__ float sW[CHID * COUT]; // 32 KiB
    __shared__ float sr[16][CHID];    // 8 KiB
    int tid = threadIdx.x;
    for (int i = tid; i < CHID * COUT; i += 256) sW[i] = W2[i];
    int nbase = blockIdx.x * 16;
    for (int i = tid; i < 16 * CHID; i += 256) {
        int nl = i >> 7;
        int j = i & 127;
        float v = t1[(long)(nbase + nl) * CHID + j];
        v = (v - mr1[j]) * mr1[CHID + j] * g[j] + be[j];
        sr[nl][j] = fmaxf(v, 0.f);
    }
    __syncthreads();
    int io = tid & 63;
    int nslot = tid >> 6;  // 4 nodes per slab
    float bb = b2[io];
    float s1 = 0.f, s2 = 0.f;
    for (int it = 0; it < 4; ++it) {
        int nl = (it << 2) + nslot;
        float acc = bb;
#pragma unroll
        for (int j = 0; j < CHID; ++j) acc = fmaf(sr[nl][j], sW[j * COUT + io], acc);
        h2[(long)(nbase + nl) * COUT + io] = acc;
        s1 += acc;
        s2 += acc * acc;
    }
    atomicAdd(&stats[io], s1);
    atomicAdd(&stats[COUT + io], s2);
}

// ---------------- GEMM3: t3 = silu(BN2(h2)) @ Wl, BN3 sums ------------------
__global__ void __launch_bounds__(256) gemm3_kernel(
        const float* __restrict__ h2, const float* __restrict__ mr2,
        const float* __restrict__ g, const float* __restrict__ be,
        const float* __restrict__ Wl,
        float* __restrict__ t3, float* __restrict__ stats) {
    __shared__ float sW[COUT * COUT]; // 16 KiB
    __shared__ float sr[16][COUT];    // 4 KiB
    int tid = threadIdx.x;
    for (int i = tid; i < COUT * COUT; i += 256) sW[i] = Wl[i];
    int nbase = blockIdx.x * 16;
    for (int i = tid; i < 16 * COUT; i += 256) {
        int nl = i >> 6;
        int j = i & 63;
        float v = h2[(long)(nbase + nl) * COUT + j];
        v = (v - mr2[j]) * mr2[COUT + j] * g[j] + be[j];
        sr[nl][j] = v / (1.f + __expf(-v));  // silu
    }
    __syncthreads();
    int io = tid & 63;
    int nslot = tid >> 6;
    float s1 = 0.f, s2 = 0.f;
    for (int it = 0; it < 4; ++it) {
        int nl = (it << 2) + nslot;
        float acc = 0.f;
#pragma unroll
        for (int j = 0; j < COUT; ++j) acc = fmaf(sr[nl][j], sW[j * COUT + io], acc);
        t3[(long)(nbase + nl) * COUT + io] = acc;
        s1 += acc;
        s2 += acc * acc;
    }
    atomicAdd(&stats[io], s1);
    atomicAdd(&stats[COUT + io], s2);
}

// ---------------- final: out = silu(BN3(t3)) --------------------------------
__global__ void final_kernel(const float* __restrict__ t3, const float* __restrict__ mr3,
                             const float* __restrict__ g, const float* __restrict__ be,
                             float* __restrict__ out) {
    long i = (long)blockIdx.x * blockDim.x + threadIdx.x;
    int j = (int)(i & 63);
    float v = t3[i];
    v = (v - mr3[j]) * mr3[COUT + j] * g[j] + be[j];
    out[i] = v / (1.f + __expf(-v));
}

extern "C" void kernel_launch(void* const* d_in, const int* in_sizes, int n_in,
                              void* d_out, int out_size, void* d_ws, size_t ws_size,
                              hipStream_t stream) {
    const float* x   = (const float*)d_in[0];
    const int*   ei  = (const int*)d_in[1];
    const float* ea  = (const float*)d_in[2];
    // d_in[3] = pos (unused by reference output path)
    const float* W1  = (const float*)d_in[4];
    const float* b1  = (const float*)d_in[5];
    const float* gm  = (const float*)d_in[6];
    const float* bm  = (const float*)d_in[7];
    const float* W2  = (const float*)d_in[8];
    const float* b2  = (const float*)d_in[9];
    const float* g1  = (const float*)d_in[10];
    const float* be1 = (const float*)d_in[11];
    const float* Wl  = (const float*)d_in[12];
    const float* g2  = (const float*)d_in[13];
    const float* be2 = (const float*)d_in[14];
    float* out = (float*)d_out;

    // workspace layout (floats):
    //   A: N*64  num -> h0 (in place) -> h2 (reused)
    //   B: N*64  den -> t3 (reused)
    //   C: N*128 t1
    //   Sraw: 512 raw sums (bn1:256, bn2:128, bn3:128) ; Sfin: 512 finalized
    float* A    = (float*)d_ws;
    float* B    = A + (long)N_NODES * CIN;
    float* C    = B + (long)N_NODES * CIN;
    float* Sraw = C + (long)N_NODES * CHID;
    float* Sfin = Sraw + 512;

    hipMemsetAsync(A, 0, (size_t)N_NODES * CIN * 2 * sizeof(float), stream);
    hipMemsetAsync(Sraw, 0, 512 * sizeof(float), stream);

    edge_pass<<<(E_EDGES * 16) / 256, 256, 0, stream>>>(x, ei, ea, A, B);
    combine_kernel<<<(N_NODES * CIN / 4) / 256, 256, 0, stream>>>(A, B, x);
    gemm1_kernel<<<N_NODES / 16, 256, 0, stream>>>(A, W1, b1, C, Sraw);
    finalize_kernel<<<1, 128, 0, stream>>>(Sraw, Sfin, CHID, 1.f / N_NODES);
    gemm2_kernel<<<N_NODES / 16, 256, 0, stream>>>(C, Sfin, gm, bm, W2, b2, A, Sraw + 256);
    finalize_kernel<<<1, 64, 0, stream>>>(Sraw + 256, Sfin + 256, COUT, 1.f / N_NODES);
    gemm3_kernel<<<N_NODES / 16, 256, 0, stream>>>(A, Sfin + 256, g1, be1, Wl, B, Sraw + 384);
    finalize_kernel<<<1, 64, 0, stream>>>(Sraw + 384, Sfin + 384, COUT, 1.f / N_NODES);
    final_kernel<<<(N_NODES * COUT) / 256, 256, 0, stream>>>(B, Sfin + 384, g2, be2, out);
}

// Round 2
// 2001.115 us; speedup vs baseline: 2.1325x; 2.1325x over previous
//
#include <hip/hip_runtime.h>

#define N_NODES 100000
#define E_EDGES 1600000
#define CIN 64
#define CHID 128
#define COUT 64
#define SCAN_CHUNK 1024

// ---------------- sort stage: counting sort of edges by dst -----------------
__global__ void hist_kernel(const int* __restrict__ ei, int* __restrict__ cnt) {
    int e = blockIdx.x * blockDim.x + threadIdx.x;
    if (e < E_EDGES) atomicAdd(&cnt[ei[E_EDGES + e]], 1);
}

__global__ void scan1_kernel(const int* __restrict__ cnt, int* __restrict__ offs,
                             int* __restrict__ chunkS) {
    __shared__ int sm[256];
    int tid = threadIdx.x;
    int base = blockIdx.x * SCAN_CHUNK + tid * 4;
    int c0 = (base + 0) < N_NODES ? cnt[base + 0] : 0;
    int c1 = (base + 1) < N_NODES ? cnt[base + 1] : 0;
    int c2 = (base + 2) < N_NODES ? cnt[base + 2] : 0;
    int c3 = (base + 3) < N_NODES ? cnt[base + 3] : 0;
    int s = c0 + c1 + c2 + c3;
    sm[tid] = s;
    __syncthreads();
    for (int off = 1; off < 256; off <<= 1) {
        int v = (tid >= off) ? sm[tid - off] : 0;
        __syncthreads();
        sm[tid] += v;
        __syncthreads();
    }
    int ex = sm[tid] - s;
    if ((base + 0) < N_NODES) offs[base + 0] = ex;
    if ((base + 1) < N_NODES) offs[base + 1] = ex + c0;
    if ((base + 2) < N_NODES) offs[base + 2] = ex + c0 + c1;
    if ((base + 3) < N_NODES) offs[base + 3] = ex + c0 + c1 + c2;
    if (tid == 255) chunkS[blockIdx.x] = sm[255];
}

__global__ void scan2_kernel(int* __restrict__ chunkS, int nchunks) {
    __shared__ int sm[256];
    int tid = threadIdx.x;
    int v = tid < nchunks ? chunkS[tid] : 0;
    sm[tid] = v;
    __syncthreads();
    for (int off = 1; off < 256; off <<= 1) {
        int t = (tid >= off) ? sm[tid - off] : 0;
        __syncthreads();
        sm[tid] += t;
        __syncthreads();
    }
    if (tid < nchunks) chunkS[tid] = sm[tid] - v;
}

__global__ void scan3_kernel(int* __restrict__ offs, const int* __restrict__ chunkS,
                             int* __restrict__ cursor) {
    int i = blockIdx.x * blockDim.x + threadIdx.x;
    if (i < N_NODES) {
        int v = offs[i] + chunkS[i >> 10];
        offs[i] = v;
        cursor[i] = v;
    }
}

__global__ void scatter_kernel(const int* __restrict__ ei, int* __restrict__ cursor,
                               int* __restrict__ eord) {
    int e = blockIdx.x * blockDim.x + threadIdx.x;
    if (e < E_EDGES) {
        int p = atomicAdd(&cursor[ei[E_EDGES + e]], 1);
        eord[p] = e;
    }
}

// ---------------- gather: softmax-aggregate per node, fuse root add --------
// aggr = sum(msg*exp(msg)) / (sum(exp(msg)) + 1e-16); exp(max) cancels vs ref.
__global__ void gather_kernel(const float* __restrict__ x, const int* __restrict__ ei,
                              const float* __restrict__ ea, const int* __restrict__ eord,
                              const int* __restrict__ offs, const int* __restrict__ cnt,
                              float* __restrict__ h0) {
    int node = (blockIdx.x * blockDim.x + threadIdx.x) >> 6;
    int lane = threadIdx.x & 63;
    if (node >= N_NODES) return;
    int s = offs[node];
    int n = cnt[node];
    float nm = 0.f, dn = 0.f;
    int eid = (n > 0) ? eord[s] : 0;
    for (int p = 0; p < n; ++p) {
        int cur = eid;
        if (p + 1 < n) eid = eord[s + p + 1];  // prefetch next edge id
        int src = ei[cur];
        float m = fmaxf(x[(long)src * CIN + lane] + ea[(long)cur * CIN + lane], 0.f) + 1e-7f;
        float ex = __expf(m);
        nm = fmaf(m, ex, nm);
        dn += ex;
    }
    h0[(long)node * CIN + lane] = nm / (dn + 1e-16f) + x[(long)node * CIN + lane];
}

// ---------------- GEMM1: t1 = h0 @ W1 + b1, accumulate BN1 sums -------------
__global__ void __launch_bounds__(256) gemm1_kernel(
        const float* __restrict__ h0, const float* __restrict__ W1,
        const float* __restrict__ b1, float* __restrict__ t1,
        float* __restrict__ stats) {
    __shared__ float sW[CIN * CHID];  // 32 KiB
    __shared__ float sh[16][CIN];     // 4 KiB
    int tid = threadIdx.x;
    for (int i = tid; i < CIN * CHID; i += 256) sW[i] = W1[i];
    int nbase = blockIdx.x * 16;
    for (int i = tid; i < 16 * CIN; i += 256) {
        int nl = i >> 6;
        sh[nl][i & 63] = h0[(long)(nbase + nl) * CIN + (i & 63)];
    }
    __syncthreads();
    int j = tid & (CHID - 1);
    int nslot = tid >> 7;
    float bb = b1[j];
    float s1 = 0.f, s2 = 0.f;
    for (int it = 0; it < 8; ++it) {
        int nl = (it << 1) + nslot;
        float acc = bb;
#pragma unroll
        for (int k = 0; k < CIN; ++k) acc = fmaf(sh[nl][k], sW[k * CHID + j], acc);
        t1[(long)(nbase + nl) * CHID + j] = acc;
        s1 += acc;
        s2 += acc * acc;
    }
    atomicAdd(&stats[j], s1);
    atomicAdd(&stats[CHID + j], s2);
}

// ---------------- finalize BN stats: mean, rsqrt(var+eps) -------------------
__global__ void finalize_kernel(const float* __restrict__ raw, float* __restrict__ mr,
                                int C, float invN) {
    int j = threadIdx.x;
    if (j < C) {
        float m = raw[j] * invN;
        float v = raw[C + j] * invN - m * m;
        mr[j] = m;
        mr[C + j] = rsqrtf(fmaxf(v, 0.f) + 1e-5f);
    }
}

// ---------------- GEMM2: h2 = relu(BN1(t1)) @ W2 + b2, BN2 sums -------------
__global__ void __launch_bounds__(256) gemm2_kernel(
        const float* __restrict__ t1, const float* __restrict__ mr1,
        const float* __restrict__ g, const float* __restrict__ be,
        const float* __restrict__ W2, const float* __restrict__ b2,
        float* __restrict__ h2, float* __restrict__ stats) {
    __shared__ float sW[CHID * COUT]; // 32 KiB
    __shared__ float sr[16][CHID];    // 8 KiB
    int tid = threadIdx.x;
    for (int i = tid; i < CHID * COUT; i += 256) sW[i] = W2[i];
    int nbase = blockIdx.x * 16;
    for (int i = tid; i < 16 * CHID; i += 256) {
        int nl = i >> 7;
        int j = i & 127;
        float v = t1[(long)(nbase + nl) * CHID + j];
        v = (v - mr1[j]) * mr1[CHID + j] * g[j] + be[j];
        sr[nl][j] = fmaxf(v, 0.f);
    }
    __syncthreads();
    int io = tid & 63;
    int nslot = tid >> 6;
    float bb = b2[io];
    float s1 = 0.f, s2 = 0.f;
    for (int it = 0; it < 4; ++it) {
        int nl = (it << 2) + nslot;
        float acc = bb;
#pragma unroll
        for (int j = 0; j < CHID; ++j) acc = fmaf(sr[nl][j], sW[j * COUT + io], acc);
        h2[(long)(nbase + nl) * COUT + io] = acc;
        s1 += acc;
        s2 += acc * acc;
    }
    atomicAdd(&stats[io], s1);
    atomicAdd(&stats[COUT + io], s2);
}

// ---------------- GEMM3: t3 = silu(BN2(h2)) @ Wl, BN3 sums ------------------
__global__ void __launch_bounds__(256) gemm3_kernel(
        const float* __restrict__ h2, const float* __restrict__ mr2,
        const float* __restrict__ g, const float* __restrict__ be,
        const float* __restrict__ Wl,
        float* __restrict__ t3, float* __restrict__ stats) {
    __shared__ float sW[COUT * COUT]; // 16 KiB
    __shared__ float sr[16][COUT];    // 4 KiB
    int tid = threadIdx.x;
    for (int i = tid; i < COUT * COUT; i += 256) sW[i] = Wl[i];
    int nbase = blockIdx.x * 16;
    for (int i = tid; i < 16 * COUT; i += 256) {
        int nl = i >> 6;
        int j = i & 63;
        float v = h2[(long)(nbase + nl) * COUT + j];
        v = (v - mr2[j]) * mr2[COUT + j] * g[j] + be[j];
        sr[nl][j] = v / (1.f + __expf(-v));  // silu
    }
    __syncthreads();
    int io = tid & 63;
    int nslot = tid >> 6;
    float s1 = 0.f, s2 = 0.f;
    for (int it = 0; it < 4; ++it) {
        int nl = (it << 2) + nslot;
        float acc = 0.f;
#pragma unroll
        for (int j = 0; j < COUT; ++j) acc = fmaf(sr[nl][j], sW[j * COUT + io], acc);
        t3[(long)(nbase + nl) * COUT + io] = acc;
        s1 += acc;
        s2 += acc * acc;
    }
    atomicAdd(&stats[io], s1);
    atomicAdd(&stats[COUT + io], s2);
}

// ---------------- final: out = silu(BN3(t3)) --------------------------------
__global__ void final_kernel(const float* __restrict__ t3, const float* __restrict__ mr3,
                             const float* __restrict__ g, const float* __restrict__ be,
                             float* __restrict__ out) {
    long i = (long)blockIdx.x * blockDim.x + threadIdx.x;
    int j = (int)(i & 63);
    float v = t3[i];
    v = (v - mr3[j]) * mr3[COUT + j] * g[j] + be[j];
    out[i] = v / (1.f + __expf(-v));
}

extern "C" void kernel_launch(void* const* d_in, const int* in_sizes, int n_in,
                              void* d_out, int out_size, void* d_ws, size_t ws_size,
                              hipStream_t stream) {
    const float* x   = (const float*)d_in[0];
    const int*   ei  = (const int*)d_in[1];
    const float* ea  = (const float*)d_in[2];
    // d_in[3] = pos (unused by reference output path)
    const float* W1  = (const float*)d_in[4];
    const float* b1  = (const float*)d_in[5];
    const float* gm  = (const float*)d_in[6];
    const float* bm  = (const float*)d_in[7];
    const float* W2  = (const float*)d_in[8];
    const float* b2  = (const float*)d_in[9];
    const float* g1  = (const float*)d_in[10];
    const float* be1 = (const float*)d_in[11];
    const float* Wl  = (const float*)d_in[12];
    const float* g2  = (const float*)d_in[13];
    const float* be2 = (const float*)d_in[14];
    float* out = (float*)d_out;

    // workspace layout (floats):
    //   h0 : N*CIN   (gather out; later reused as t3)
    //   t1 : N*CHID  (gemm1 out; its space first hosts the sort arrays)
    //   h2 : N*COUT  (gemm2 out)
    //   stats: raw 512 + finalized 512
    float* h0 = (float*)d_ws;
    float* t1 = h0 + (long)N_NODES * CIN;
    float* h2 = t1 + (long)N_NODES * CHID;
    float* t3 = h0;  // alias: h0 dead after gemm1
    float* Sraw = h2 + (long)N_NODES * COUT;
    float* Sfin = Sraw + 512;
    // sort arrays live inside t1's region (dead once gemm1 writes t1)
    int* eord   = (int*)t1;
    int* cnt    = eord + E_EDGES;
    int* offs   = cnt + N_NODES;
    int* cursor = offs + N_NODES;
    int* chunkS = cursor + N_NODES;

    const int nchunks = (N_NODES + SCAN_CHUNK - 1) / SCAN_CHUNK;  // 98

    hipMemsetAsync(cnt, 0, (size_t)N_NODES * sizeof(int), stream);
    hipMemsetAsync(Sraw, 0, 512 * sizeof(float), stream);

    hist_kernel<<<(E_EDGES + 255) / 256, 256, 0, stream>>>(ei, cnt);
    scan1_kernel<<<nchunks, 256, 0, stream>>>(cnt, offs, chunkS);
    scan2_kernel<<<1, 256, 0, stream>>>(chunkS, nchunks);
    scan3_kernel<<<(N_NODES + 255) / 256, 256, 0, stream>>>(offs, chunkS, cursor);
    scatter_kernel<<<(E_EDGES + 255) / 256, 256, 0, stream>>>(ei, cursor, eord);
    gather_kernel<<<(N_NODES * 64 + 255) / 256, 256, 0, stream>>>(x, ei, ea, eord, offs, cnt, h0);

    gemm1_kernel<<<N_NODES / 16, 256, 0, stream>>>(h0, W1, b1, t1, Sraw);
    finalize_kernel<<<1, 128, 0, stream>>>(Sraw, Sfin, CHID, 1.f / N_NODES);
    gemm2_kernel<<<N_NODES / 16, 256, 0, stream>>>(t1, Sfin, gm, bm, W2, b2, h2, Sraw + 256);
    finalize_kernel<<<1, 64, 0, stream>>>(Sraw + 256, Sfin + 256, COUT, 1.f / N_NODES);
    gemm3_kernel<<<N_NODES / 16, 256, 0, stream>>>(h2, Sfin + 256, g1, be1, Wl, t3, Sraw + 384);
    finalize_kernel<<<1, 64, 0, stream>>>(Sraw + 384, Sfin + 384, COUT, 1.f / N_NODES);
    final_kernel<<<(N_NODES * COUT) / 256, 256, 0, stream>>>(t3, Sfin + 384, g2, be2, out);
}

// Round 3
// 715.381 us; speedup vs baseline: 5.9651x; 2.7973x over previous
//
#include <hip/hip_runtime.h>

#define N_NODES 100000
#define E_EDGES 1600000
#define CIN 64
#define CHID 128
#define COUT 64
#define SCAN_CHUNK 1024
#define NT 64                      // nodes per GEMM block
#define NB ((N_NODES + NT - 1) / NT)  // 1563

// ---------------- sort stage: counting sort of edges by dst -----------------
__global__ void hist_kernel(const int* __restrict__ ei, int* __restrict__ cnt) {
    int e = blockIdx.x * blockDim.x + threadIdx.x;
    if (e < E_EDGES) atomicAdd(&cnt[ei[E_EDGES + e]], 1);
}

__global__ void scan1_kernel(const int* __restrict__ cnt, int* __restrict__ offs,
                             int* __restrict__ chunkS) {
    __shared__ int sm[256];
    int tid = threadIdx.x;
    int base = blockIdx.x * SCAN_CHUNK + tid * 4;
    int c0 = (base + 0) < N_NODES ? cnt[base + 0] : 0;
    int c1 = (base + 1) < N_NODES ? cnt[base + 1] : 0;
    int c2 = (base + 2) < N_NODES ? cnt[base + 2] : 0;
    int c3 = (base + 3) < N_NODES ? cnt[base + 3] : 0;
    int s = c0 + c1 + c2 + c3;
    sm[tid] = s;
    __syncthreads();
    for (int off = 1; off < 256; off <<= 1) {
        int v = (tid >= off) ? sm[tid - off] : 0;
        __syncthreads();
        sm[tid] += v;
        __syncthreads();
    }
    int ex = sm[tid] - s;
    if ((base + 0) < N_NODES) offs[base + 0] = ex;
    if ((base + 1) < N_NODES) offs[base + 1] = ex + c0;
    if ((base + 2) < N_NODES) offs[base + 2] = ex + c0 + c1;
    if ((base + 3) < N_NODES) offs[base + 3] = ex + c0 + c1 + c2;
    if (tid == 255) chunkS[blockIdx.x] = sm[255];
}

__global__ void scan2_kernel(int* __restrict__ chunkS, int nchunks) {
    __shared__ int sm[256];
    int tid = threadIdx.x;
    int v = tid < nchunks ? chunkS[tid] : 0;
    sm[tid] = v;
    __syncthreads();
    for (int off = 1; off < 256; off <<= 1) {
        int t = (tid >= off) ? sm[tid - off] : 0;
        __syncthreads();
        sm[tid] += t;
        __syncthreads();
    }
    if (tid < nchunks) chunkS[tid] = sm[tid] - v;
}

__global__ void scan3_kernel(int* __restrict__ offs, const int* __restrict__ chunkS,
                             int* __restrict__ cursor) {
    int i = blockIdx.x * blockDim.x + threadIdx.x;
    if (i < N_NODES) {
        int v = offs[i] + chunkS[i >> 10];
        offs[i] = v;
        cursor[i] = v;
    }
}

__global__ void scatter_kernel(const int* __restrict__ ei, int* __restrict__ cursor,
                               int* __restrict__ eord) {
    int e = blockIdx.x * blockDim.x + threadIdx.x;
    if (e < E_EDGES) {
        int p = atomicAdd(&cursor[ei[E_EDGES + e]], 1);
        eord[p] = e;
    }
}

// ---------------- gather: softmax-aggregate per node, fuse root add --------
__global__ void gather_kernel(const float* __restrict__ x, const int* __restrict__ ei,
                              const float* __restrict__ ea, const int* __restrict__ eord,
                              const int* __restrict__ offs, const int* __restrict__ cnt,
                              float* __restrict__ h0) {
    int node = (blockIdx.x * blockDim.x + threadIdx.x) >> 6;
    int lane = threadIdx.x & 63;
    if (node >= N_NODES) return;
    int s = offs[node];
    int n = cnt[node];
    float nm = 0.f, dn = 0.f;
    int eid = (n > 0) ? eord[s] : 0;
    for (int p = 0; p < n; ++p) {
        int cur = eid;
        if (p + 1 < n) eid = eord[s + p + 1];
        int src = ei[cur];
        float m = fmaxf(x[(long)src * CIN + lane] + ea[(long)cur * CIN + lane], 0.f) + 1e-7f;
        float ex = __expf(m);
        nm = fmaf(m, ex, nm);
        dn += ex;
    }
    h0[(long)node * CIN + lane] = nm / (dn + 1e-16f) + x[(long)node * CIN + lane];
}

// ---------------- channel-stat reduce: partial rows -> mean, rsqrt ----------
__global__ void __launch_bounds__(256) reduce_kernel(const float* __restrict__ P,
                                                     int totrows, int C,
                                                     float* __restrict__ mr, float invN) {
    int c = blockIdx.x;
    int t = threadIdx.x;
    float s1 = 0.f, s2 = 0.f;
    for (int row = t; row < totrows; row += 256) {
        s1 += P[(long)row * 2 * C + c];
        s2 += P[(long)row * 2 * C + C + c];
    }
    __shared__ float rs1[256], rs2[256];
    rs1[t] = s1; rs2[t] = s2;
    __syncthreads();
    for (int off = 128; off > 0; off >>= 1) {
        if (t < off) { rs1[t] += rs1[t + off]; rs2[t] += rs2[t + off]; }
        __syncthreads();
    }
    if (t == 0) {
        float m = rs1[0] * invN;
        float v = rs2[0] * invN - m * m;
        mr[c] = m;
        mr[C + c] = rsqrtf(fmaxf(v, 0.f) + 1e-5f);
    }
}

// ---------------- GEMM1: t1 = h0 @ W1 + b1, partial BN1 sums ----------------
// 64 nodes/block; thread: 4 out-ch (js) x 8 nodes (group r). No atomics.
__global__ void __launch_bounds__(256) gemm1_kernel(
        const float* __restrict__ h0, const float* __restrict__ W1,
        const float* __restrict__ b1, float* __restrict__ t1,
        float* __restrict__ P) {
    __shared__ float sW[CIN * CHID];  // 32 KiB
    __shared__ float sh[NT * CIN];    // 16 KiB
    int tid = threadIdx.x;
    int nbase = blockIdx.x * NT;
    for (int i = tid * 4; i < CIN * CHID; i += 1024)
        *(float4*)&sW[i] = *(const float4*)&W1[i];
    for (int i = tid * 4; i < NT * CIN; i += 1024) {
        int node = nbase + (i >> 6);
        float4 v = make_float4(0.f, 0.f, 0.f, 0.f);
        if (node < N_NODES) v = *(const float4*)&h0[(long)node * CIN + (i & 63)];
        *(float4*)&sh[i] = v;
    }
    __syncthreads();
    int js = (tid & 31) * 4;  // out channels js..js+3
    int r  = tid >> 5;        // node group, nodes r*8 .. r*8+7
    float4 bb = *(const float4*)&b1[js];
    float acc[8][4];
#pragma unroll
    for (int i = 0; i < 8; ++i) { acc[i][0]=bb.x; acc[i][1]=bb.y; acc[i][2]=bb.z; acc[i][3]=bb.w; }
#pragma unroll 4
    for (int k = 0; k < CIN; ++k) {
        float4 w = *(float4*)&sW[k * CHID + js];
#pragma unroll
        for (int i = 0; i < 8; ++i) {
            float a = sh[(r * 8 + i) * CIN + k];
            acc[i][0] = fmaf(a, w.x, acc[i][0]);
            acc[i][1] = fmaf(a, w.y, acc[i][1]);
            acc[i][2] = fmaf(a, w.z, acc[i][2]);
            acc[i][3] = fmaf(a, w.w, acc[i][3]);
        }
    }
    float s1[4] = {0,0,0,0}, s2[4] = {0,0,0,0};
#pragma unroll
    for (int i = 0; i < 8; ++i) {
        int node = nbase + r * 8 + i;
        if (node < N_NODES) {
            *(float4*)&t1[(long)node * CHID + js] =
                make_float4(acc[i][0], acc[i][1], acc[i][2], acc[i][3]);
#pragma unroll
            for (int jj = 0; jj < 4; ++jj) {
                s1[jj] += acc[i][jj];
                s2[jj] += acc[i][jj] * acc[i][jj];
            }
        }
    }
    float* p = P + (long)blockIdx.x * 2048 + r * 256;  // 8 rows x 256
    *(float4*)&p[js]       = make_float4(s1[0], s1[1], s1[2], s1[3]);
    *(float4*)&p[128 + js] = make_float4(s2[0], s2[1], s2[2], s2[3]);
}

// ---------------- GEMM2: h2 = relu(BN1(t1)) @ W2 + b2, partial BN2 sums -----
__global__ void __launch_bounds__(256) gemm2_kernel(
        const float* __restrict__ t1, const float* __restrict__ mr1,
        const float* __restrict__ g, const float* __restrict__ be,
        const float* __restrict__ W2, const float* __restrict__ b2,
        float* __restrict__ h2, float* __restrict__ P) {
    __shared__ float sW[CHID * COUT]; // 32 KiB
    __shared__ float sr[NT * CHID];   // 32 KiB
    int tid = threadIdx.x;
    int nbase = blockIdx.x * NT;
    for (int i = tid * 4; i < CHID * COUT; i += 1024)
        *(float4*)&sW[i] = *(const float4*)&W2[i];
    for (int i = tid * 4; i < NT * CHID; i += 1024) {
        int node = nbase + (i >> 7);
        int j = i & 127;
        float4 v = make_float4(0.f, 0.f, 0.f, 0.f);
        if (node < N_NODES) {
            v = *(const float4*)&t1[(long)node * CHID + j];
            float4 mn = *(const float4*)&mr1[j];
            float4 rq = *(const float4*)&mr1[CHID + j];
            float4 gg = *(const float4*)&g[j];
            float4 bb = *(const float4*)&be[j];
            v.x = fmaxf((v.x - mn.x) * rq.x * gg.x + bb.x, 0.f);
            v.y = fmaxf((v.y - mn.y) * rq.y * gg.y + bb.y, 0.f);
            v.z = fmaxf((v.z - mn.z) * rq.z * gg.z + bb.z, 0.f);
            v.w = fmaxf((v.w - mn.w) * rq.w * gg.w + bb.w, 0.f);
        }
        *(float4*)&sr[i] = v;
    }
    __syncthreads();
    int js = (tid & 15) * 4;  // out channels
    int r  = tid >> 4;        // node group, nodes r*4 .. r*4+3
    float4 bb = *(const float4*)&b2[js];
    float acc[4][4];
#pragma unroll
    for (int i = 0; i < 4; ++i) { acc[i][0]=bb.x; acc[i][1]=bb.y; acc[i][2]=bb.z; acc[i][3]=bb.w; }
#pragma unroll 4
    for (int k = 0; k < CHID; ++k) {
        float4 w = *(float4*)&sW[k * COUT + js];
#pragma unroll
        for (int i = 0; i < 4; ++i) {
            float a = sr[(r * 4 + i) * CHID + k];
            acc[i][0] = fmaf(a, w.x, acc[i][0]);
            acc[i][1] = fmaf(a, w.y, acc[i][1]);
            acc[i][2] = fmaf(a, w.z, acc[i][2]);
            acc[i][3] = fmaf(a, w.w, acc[i][3]);
        }
    }
    float s1[4] = {0,0,0,0}, s2[4] = {0,0,0,0};
#pragma unroll
    for (int i = 0; i < 4; ++i) {
        int node = nbase + r * 4 + i;
        if (node < N_NODES) {
            *(float4*)&h2[(long)node * COUT + js] =
                make_float4(acc[i][0], acc[i][1], acc[i][2], acc[i][3]);
#pragma unroll
            for (int jj = 0; jj < 4; ++jj) {
                s1[jj] += acc[i][jj];
                s2[jj] += acc[i][jj] * acc[i][jj];
            }
        }
    }
    float* p = P + (long)blockIdx.x * 2048 + r * 128;  // 16 rows x 128
    *(float4*)&p[js]      = make_float4(s1[0], s1[1], s1[2], s1[3]);
    *(float4*)&p[64 + js] = make_float4(s2[0], s2[1], s2[2], s2[3]);
}

// ---------------- GEMM3: t3 = silu(BN2(h2)) @ Wl, partial BN3 sums ----------
__global__ void __launch_bounds__(256) gemm3_kernel(
        const float* __restrict__ h2, const float* __restrict__ mr2,
        const float* __restrict__ g, const float* __restrict__ be,
        const float* __restrict__ Wl,
        float* __restrict__ t3, float* __restrict__ P) {
    __shared__ float sW[COUT * COUT]; // 16 KiB
    __shared__ float sr[NT * COUT];   // 16 KiB
    int tid = threadIdx.x;
    int nbase = blockIdx.x * NT;
    for (int i = tid * 4; i < COUT * COUT; i += 1024)
        *(float4*)&sW[i] = *(const float4*)&Wl[i];
    for (int i = tid * 4; i < NT * COUT; i += 1024) {
        int node = nbase + (i >> 6);
        int j = i & 63;
        float4 v = make_float4(0.f, 0.f, 0.f, 0.f);
        if (node < N_NODES) {
            v = *(const float4*)&h2[(long)node * COUT + j];
            float4 mn = *(const float4*)&mr2[j];
            float4 rq = *(const float4*)&mr2[COUT + j];
            float4 gg = *(const float4*)&g[j];
            float4 bb = *(const float4*)&be[j];
            v.x = (v.x - mn.x) * rq.x * gg.x + bb.x;
            v.y = (v.y - mn.y) * rq.y * gg.y + bb.y;
            v.z = (v.z - mn.z) * rq.z * gg.z + bb.z;
            v.w = (v.w - mn.w) * rq.w * gg.w + bb.w;
            v.x = v.x / (1.f + __expf(-v.x));
            v.y = v.y / (1.f + __expf(-v.y));
            v.z = v.z / (1.f + __expf(-v.z));
            v.w = v.w / (1.f + __expf(-v.w));
        }
        *(float4*)&sr[i] = v;
    }
    __syncthreads();
    int js = (tid & 15) * 4;
    int r  = tid >> 4;
    float acc[4][4];
#pragma unroll
    for (int i = 0; i < 4; ++i) { acc[i][0]=0.f; acc[i][1]=0.f; acc[i][2]=0.f; acc[i][3]=0.f; }
#pragma unroll 4
    for (int k = 0; k < COUT; ++k) {
        float4 w = *(float4*)&sW[k * COUT + js];
#pragma unroll
        for (int i = 0; i < 4; ++i) {
            float a = sr[(r * 4 + i) * COUT + k];
            acc[i][0] = fmaf(a, w.x, acc[i][0]);
            acc[i][1] = fmaf(a, w.y, acc[i][1]);
            acc[i][2] = fmaf(a, w.z, acc[i][2]);
            acc[i][3] = fmaf(a, w.w, acc[i][3]);
        }
    }
    float s1[4] = {0,0,0,0}, s2[4] = {0,0,0,0};
#pragma unroll
    for (int i = 0; i < 4; ++i) {
        int node = nbase + r * 4 + i;
        if (node < N_NODES) {
            *(float4*)&t3[(long)node * COUT + js] =
                make_float4(acc[i][0], acc[i][1], acc[i][2], acc[i][3]);
#pragma unroll
            for (int jj = 0; jj < 4; ++jj) {
                s1[jj] += acc[i][jj];
                s2[jj] += acc[i][jj] * acc[i][jj];
            }
        }
    }
    float* p = P + (long)blockIdx.x * 2048 + r * 128;
    *(float4*)&p[js]      = make_float4(s1[0], s1[1], s1[2], s1[3]);
    *(float4*)&p[64 + js] = make_float4(s2[0], s2[1], s2[2], s2[3]);
}

// ---------------- final: out = silu(BN3(t3)) --------------------------------
__global__ void final_kernel(const float* __restrict__ t3, const float* __restrict__ mr3,
                             const float* __restrict__ g, const float* __restrict__ be,
                             float* __restrict__ out) {
    long i = (long)blockIdx.x * blockDim.x + threadIdx.x;
    int j = (int)(i & 63);
    float v = t3[i];
    v = (v - mr3[j]) * mr3[COUT + j] * g[j] + be[j];
    out[i] = v / (1.f + __expf(-v));
}

extern "C" void kernel_launch(void* const* d_in, const int* in_sizes, int n_in,
                              void* d_out, int out_size, void* d_ws, size_t ws_size,
                              hipStream_t stream) {
    const float* x   = (const float*)d_in[0];
    const int*   ei  = (const int*)d_in[1];
    const float* ea  = (const float*)d_in[2];
    const float* W1  = (const float*)d_in[4];
    const float* b1  = (const float*)d_in[5];
    const float* gm  = (const float*)d_in[6];
    const float* bm  = (const float*)d_in[7];
    const float* W2  = (const float*)d_in[8];
    const float* b2  = (const float*)d_in[9];
    const float* g1  = (const float*)d_in[10];
    const float* be1 = (const float*)d_in[11];
    const float* Wl  = (const float*)d_in[12];
    const float* g2  = (const float*)d_in[13];
    const float* be2 = (const float*)d_in[14];
    float* out = (float*)d_out;

    // workspace: h0[N*64] | t1[N*128] | h2[N*64] | Sfin[512]
    // stat-partial arrays alias dead regions:
    //   P1 -> h2 region, P2 -> h0 region, P3 -> t1 region (each 1563*2048 f)
    float* h0 = (float*)d_ws;
    float* t1 = h0 + (long)N_NODES * CIN;
    float* h2 = t1 + (long)N_NODES * CHID;
    float* t3 = h0;
    float* Sfin = h2 + (long)N_NODES * COUT;
    float* P1 = h2;
    float* P2 = h0;
    float* P3 = t1;
    // sort arrays live in t1 region (dead until gemm1 writes t1)
    int* eord   = (int*)t1;
    int* cnt    = eord + E_EDGES;
    int* offs   = cnt + N_NODES;
    int* cursor = offs + N_NODES;
    int* chunkS = cursor + N_NODES;

    const int nchunks = (N_NODES + SCAN_CHUNK - 1) / SCAN_CHUNK;
    const float invN = 1.f / N_NODES;

    hipMemsetAsync(cnt, 0, (size_t)N_NODES * sizeof(int), stream);

    hist_kernel<<<(E_EDGES + 255) / 256, 256, 0, stream>>>(ei, cnt);
    scan1_kernel<<<nchunks, 256, 0, stream>>>(cnt, offs, chunkS);
    scan2_kernel<<<1, 256, 0, stream>>>(chunkS, nchunks);
    scan3_kernel<<<(N_NODES + 255) / 256, 256, 0, stream>>>(offs, chunkS, cursor);
    scatter_kernel<<<(E_EDGES + 255) / 256, 256, 0, stream>>>(ei, cursor, eord);
    gather_kernel<<<(N_NODES * 64 + 255) / 256, 256, 0, stream>>>(x, ei, ea, eord, offs, cnt, h0);

    gemm1_kernel<<<NB, 256, 0, stream>>>(h0, W1, b1, t1, P1);
    reduce_kernel<<<CHID, 256, 0, stream>>>(P1, NB * 8, CHID, Sfin, invN);
    gemm2_kernel<<<NB, 256, 0, stream>>>(t1, Sfin, gm, bm, W2, b2, h2, P2);
    reduce_kernel<<<COUT, 256, 0, stream>>>(P2, NB * 16, COUT, Sfin + 256, invN);
    gemm3_kernel<<<NB, 256, 0, stream>>>(h2, Sfin + 256, g1, be1, Wl, t3, P3);
    reduce_kernel<<<COUT, 256, 0, stream>>>(P3, NB * 16, COUT, Sfin + 384, invN);
    final_kernel<<<(N_NODES * COUT) / 256, 256, 0, stream>>>(t3, Sfin + 384, g2, be2, out);
}

// Round 4
// 569.359 us; speedup vs baseline: 7.4950x; 1.2565x over previous
//
#include <hip/hip_runtime.h>

#define N_NODES 100000
#define E_EDGES 1600000
#define CIN 64
#define CHID 128
#define COUT 64
#define SCAN_CHUNK 1024
#define NT 64                      // nodes per GEMM block
#define NB ((N_NODES + NT - 1) / NT)  // 1563

// ---------------- sort stage: counting sort of edges by dst -----------------
__global__ void hist_kernel(const int* __restrict__ ei, int* __restrict__ cnt) {
    int e = blockIdx.x * blockDim.x + threadIdx.x;
    if (e < E_EDGES) atomicAdd(&cnt[ei[E_EDGES + e]], 1);
}

__global__ void scan1_kernel(const int* __restrict__ cnt, int* __restrict__ offs,
                             int* __restrict__ chunkS) {
    __shared__ int sm[256];
    int tid = threadIdx.x;
    int base = blockIdx.x * SCAN_CHUNK + tid * 4;
    int c0 = (base + 0) < N_NODES ? cnt[base + 0] : 0;
    int c1 = (base + 1) < N_NODES ? cnt[base + 1] : 0;
    int c2 = (base + 2) < N_NODES ? cnt[base + 2] : 0;
    int c3 = (base + 3) < N_NODES ? cnt[base + 3] : 0;
    int s = c0 + c1 + c2 + c3;
    sm[tid] = s;
    __syncthreads();
    for (int off = 1; off < 256; off <<= 1) {
        int v = (tid >= off) ? sm[tid - off] : 0;
        __syncthreads();
        sm[tid] += v;
        __syncthreads();
    }
    int ex = sm[tid] - s;
    if ((base + 0) < N_NODES) offs[base + 0] = ex;
    if ((base + 1) < N_NODES) offs[base + 1] = ex + c0;
    if ((base + 2) < N_NODES) offs[base + 2] = ex + c0 + c1;
    if ((base + 3) < N_NODES) offs[base + 3] = ex + c0 + c1 + c2;
    if (tid == 255) chunkS[blockIdx.x] = sm[255];
}

__global__ void scan2_kernel(int* __restrict__ chunkS, int nchunks) {
    __shared__ int sm[256];
    int tid = threadIdx.x;
    int v = tid < nchunks ? chunkS[tid] : 0;
    sm[tid] = v;
    __syncthreads();
    for (int off = 1; off < 256; off <<= 1) {
        int t = (tid >= off) ? sm[tid - off] : 0;
        __syncthreads();
        sm[tid] += t;
        __syncthreads();
    }
    if (tid < nchunks) chunkS[tid] = sm[tid] - v;
}

__global__ void scan3_kernel(int* __restrict__ offs, const int* __restrict__ chunkS,
                             int* __restrict__ cursor) {
    int i = blockIdx.x * blockDim.x + threadIdx.x;
    if (i < N_NODES) {
        int v = offs[i] + chunkS[i >> 10];
        offs[i] = v;
        cursor[i] = v;
    }
}

// scatter {edge id, src} to dst-sorted position
__global__ void scatter_kernel(const int* __restrict__ ei, int* __restrict__ cursor,
                               int2* __restrict__ es) {
    int e = blockIdx.x * blockDim.x + threadIdx.x;
    if (e < E_EDGES) {
        int src = ei[e];
        int dst = ei[E_EDGES + e];
        int p = atomicAdd(&cursor[dst], 1);
        es[p] = make_int2(e, src);
    }
}

// ---------------- gather: softmax-aggregate per node, fuse root add --------
// aggr = sum(msg*exp(msg)) / (sum(exp(msg)) + 1e-16); exp(max) cancels vs ref.
// Unrolled 4x: 8 independent row loads in flight per wave (MLP).
__global__ void gather_kernel(const float* __restrict__ x,
                              const float* __restrict__ ea,
                              const int2* __restrict__ es,
                              const int* __restrict__ offs, const int* __restrict__ cnt,
                              float* __restrict__ h0) {
    int node = (blockIdx.x * blockDim.x + threadIdx.x) >> 6;
    int lane = threadIdx.x & 63;
    if (node >= N_NODES) return;
    int s = offs[node];
    int n = cnt[node];
    float nm = 0.f, dn = 0.f;
    int p = 0;
    for (; p + 4 <= n; p += 4) {
        int2 q0 = es[s + p + 0];
        int2 q1 = es[s + p + 1];
        int2 q2 = es[s + p + 2];
        int2 q3 = es[s + p + 3];
        float a0 = ea[(long)q0.x * CIN + lane];
        float a1 = ea[(long)q1.x * CIN + lane];
        float a2 = ea[(long)q2.x * CIN + lane];
        float a3 = ea[(long)q3.x * CIN + lane];
        float x0 = x[(long)q0.y * CIN + lane];
        float x1 = x[(long)q1.y * CIN + lane];
        float x2 = x[(long)q2.y * CIN + lane];
        float x3 = x[(long)q3.y * CIN + lane];
        float m0 = fmaxf(x0 + a0, 0.f) + 1e-7f;
        float m1 = fmaxf(x1 + a1, 0.f) + 1e-7f;
        float m2 = fmaxf(x2 + a2, 0.f) + 1e-7f;
        float m3 = fmaxf(x3 + a3, 0.f) + 1e-7f;
        float e0 = __expf(m0), e1 = __expf(m1), e2 = __expf(m2), e3 = __expf(m3);
        nm = fmaf(m0, e0, nm); dn += e0;
        nm = fmaf(m1, e1, nm); dn += e1;
        nm = fmaf(m2, e2, nm); dn += e2;
        nm = fmaf(m3, e3, nm); dn += e3;
    }
    for (; p < n; ++p) {
        int2 q = es[s + p];
        float m = fmaxf(x[(long)q.y * CIN + lane] + ea[(long)q.x * CIN + lane], 0.f) + 1e-7f;
        float ex = __expf(m);
        nm = fmaf(m, ex, nm);
        dn += ex;
    }
    h0[(long)node * CIN + lane] = nm / (dn + 1e-16f) + x[(long)node * CIN + lane];
}

// ---------------- channel-stat reduce: partial rows -> mean, rsqrt ----------
__global__ void __launch_bounds__(256) reduce_kernel(const float* __restrict__ P,
                                                     int totrows, int C,
                                                     float* __restrict__ mr, float invN) {
    int c = blockIdx.x;
    int t = threadIdx.x;
    float s1 = 0.f, s2 = 0.f;
    for (int row = t; row < totrows; row += 256) {
        s1 += P[(long)row * 2 * C + c];
        s2 += P[(long)row * 2 * C + C + c];
    }
    __shared__ float rs1[256], rs2[256];
    rs1[t] = s1; rs2[t] = s2;
    __syncthreads();
    for (int off = 128; off > 0; off >>= 1) {
        if (t < off) { rs1[t] += rs1[t + off]; rs2[t] += rs2[t + off]; }
        __syncthreads();
    }
    if (t == 0) {
        float m = rs1[0] * invN;
        float v = rs2[0] * invN - m * m;
        mr[c] = m;
        mr[C + c] = rsqrtf(fmaxf(v, 0.f) + 1e-5f);
    }
}

// ---------------- GEMM1: t1 = h0 @ W1 + b1, partial BN1 sums ----------------
__global__ void __launch_bounds__(256) gemm1_kernel(
        const float* __restrict__ h0, const float* __restrict__ W1,
        const float* __restrict__ b1, float* __restrict__ t1,
        float* __restrict__ P) {
    __shared__ float sW[CIN * CHID];  // 32 KiB
    __shared__ float sh[NT * CIN];    // 16 KiB
    int tid = threadIdx.x;
    int nbase = blockIdx.x * NT;
    for (int i = tid * 4; i < CIN * CHID; i += 1024)
        *(float4*)&sW[i] = *(const float4*)&W1[i];
    for (int i = tid * 4; i < NT * CIN; i += 1024) {
        int node = nbase + (i >> 6);
        float4 v = make_float4(0.f, 0.f, 0.f, 0.f);
        if (node < N_NODES) v = *(const float4*)&h0[(long)node * CIN + (i & 63)];
        *(float4*)&sh[i] = v;
    }
    __syncthreads();
    int js = (tid & 31) * 4;  // out channels js..js+3
    int r  = tid >> 5;        // node group, nodes r*8 .. r*8+7
    float4 bb = *(const float4*)&b1[js];
    float acc[8][4];
#pragma unroll
    for (int i = 0; i < 8; ++i) { acc[i][0]=bb.x; acc[i][1]=bb.y; acc[i][2]=bb.z; acc[i][3]=bb.w; }
#pragma unroll 4
    for (int k = 0; k < CIN; ++k) {
        float4 w = *(float4*)&sW[k * CHID + js];
#pragma unroll
        for (int i = 0; i < 8; ++i) {
            float a = sh[(r * 8 + i) * CIN + k];
            acc[i][0] = fmaf(a, w.x, acc[i][0]);
            acc[i][1] = fmaf(a, w.y, acc[i][1]);
            acc[i][2] = fmaf(a, w.z, acc[i][2]);
            acc[i][3] = fmaf(a, w.w, acc[i][3]);
        }
    }
    float s1[4] = {0,0,0,0}, s2[4] = {0,0,0,0};
#pragma unroll
    for (int i = 0; i < 8; ++i) {
        int node = nbase + r * 8 + i;
        if (node < N_NODES) {
            *(float4*)&t1[(long)node * CHID + js] =
                make_float4(acc[i][0], acc[i][1], acc[i][2], acc[i][3]);
#pragma unroll
            for (int jj = 0; jj < 4; ++jj) {
                s1[jj] += acc[i][jj];
                s2[jj] += acc[i][jj] * acc[i][jj];
            }
        }
    }
    float* p = P + (long)blockIdx.x * 2048 + r * 256;  // 8 rows x 256
    *(float4*)&p[js]       = make_float4(s1[0], s1[1], s1[2], s1[3]);
    *(float4*)&p[128 + js] = make_float4(s2[0], s2[1], s2[2], s2[3]);
}

// ---------------- GEMM2: h2 = relu(BN1(t1)) @ W2 + b2, partial BN2 sums -----
__global__ void __launch_bounds__(256) gemm2_kernel(
        const float* __restrict__ t1, const float* __restrict__ mr1,
        const float* __restrict__ g, const float* __restrict__ be,
        const float* __restrict__ W2, const float* __restrict__ b2,
        float* __restrict__ h2, float* __restrict__ P) {
    __shared__ float sW[CHID * COUT]; // 32 KiB
    __shared__ float sr[NT * CHID];   // 32 KiB
    int tid = threadIdx.x;
    int nbase = blockIdx.x * NT;
    for (int i = tid * 4; i < CHID * COUT; i += 1024)
        *(float4*)&sW[i] = *(const float4*)&W2[i];
    for (int i = tid * 4; i < NT * CHID; i += 1024) {
        int node = nbase + (i >> 7);
        int j = i & 127;
        float4 v = make_float4(0.f, 0.f, 0.f, 0.f);
        if (node < N_NODES) {
            v = *(const float4*)&t1[(long)node * CHID + j];
            float4 mn = *(const float4*)&mr1[j];
            float4 rq = *(const float4*)&mr1[CHID + j];
            float4 gg = *(const float4*)&g[j];
            float4 bb = *(const float4*)&be[j];
            v.x = fmaxf((v.x - mn.x) * rq.x * gg.x + bb.x, 0.f);
            v.y = fmaxf((v.y - mn.y) * rq.y * gg.y + bb.y, 0.f);
            v.z = fmaxf((v.z - mn.z) * rq.z * gg.z + bb.z, 0.f);
            v.w = fmaxf((v.w - mn.w) * rq.w * gg.w + bb.w, 0.f);
        }
        *(float4*)&sr[i] = v;
    }
    __syncthreads();
    int js = (tid & 15) * 4;  // out channels
    int r  = tid >> 4;        // node group, nodes r*4 .. r*4+3
    float4 bb = *(const float4*)&b2[js];
    float acc[4][4];
#pragma unroll
    for (int i = 0; i < 4; ++i) { acc[i][0]=bb.x; acc[i][1]=bb.y; acc[i][2]=bb.z; acc[i][3]=bb.w; }
#pragma unroll 4
    for (int k = 0; k < CHID; ++k) {
        float4 w = *(float4*)&sW[k * COUT + js];
#pragma unroll
        for (int i = 0; i < 4; ++i) {
            float a = sr[(r * 4 + i) * CHID + k];
            acc[i][0] = fmaf(a, w.x, acc[i][0]);
            acc[i][1] = fmaf(a, w.y, acc[i][1]);
            acc[i][2] = fmaf(a, w.z, acc[i][2]);
            acc[i][3] = fmaf(a, w.w, acc[i][3]);
        }
    }
    float s1[4] = {0,0,0,0}, s2[4] = {0,0,0,0};
#pragma unroll
    for (int i = 0; i < 4; ++i) {
        int node = nbase + r * 4 + i;
        if (node < N_NODES) {
            *(float4*)&h2[(long)node * COUT + js] =
                make_float4(acc[i][0], acc[i][1], acc[i][2], acc[i][3]);
#pragma unroll
            for (int jj = 0; jj < 4; ++jj) {
                s1[jj] += acc[i][jj];
                s2[jj] += acc[i][jj] * acc[i][jj];
            }
        }
    }
    float* p = P + (long)blockIdx.x * 2048 + r * 128;  // 16 rows x 128
    *(float4*)&p[js]      = make_float4(s1[0], s1[1], s1[2], s1[3]);
    *(float4*)&p[64 + js] = make_float4(s2[0], s2[1], s2[2], s2[3]);
}

// ---------------- GEMM3: t3 = silu(BN2(h2)) @ Wl, partial BN3 sums ----------
__global__ void __launch_bounds__(256) gemm3_kernel(
        const float* __restrict__ h2, const float* __restrict__ mr2,
        const float* __restrict__ g, const float* __restrict__ be,
        const float* __restrict__ Wl,
        float* __restrict__ t3, float* __restrict__ P) {
    __shared__ float sW[COUT * COUT]; // 16 KiB
    __shared__ float sr[NT * COUT];   // 16 KiB
    int tid = threadIdx.x;
    int nbase = blockIdx.x * NT;
    for (int i = tid * 4; i < COUT * COUT; i += 1024)
        *(float4*)&sW[i] = *(const float4*)&Wl[i];
    for (int i = tid * 4; i < NT * COUT; i += 1024) {
        int node = nbase + (i >> 6);
        int j = i & 63;
        float4 v = make_float4(0.f, 0.f, 0.f, 0.f);
        if (node < N_NODES) {
            v = *(const float4*)&h2[(long)node * COUT + j];
            float4 mn = *(const float4*)&mr2[j];
            float4 rq = *(const float4*)&mr2[COUT + j];
            float4 gg = *(const float4*)&g[j];
            float4 bb = *(const float4*)&be[j];
            v.x = (v.x - mn.x) * rq.x * gg.x + bb.x;
            v.y = (v.y - mn.y) * rq.y * gg.y + bb.y;
            v.z = (v.z - mn.z) * rq.z * gg.z + bb.z;
            v.w = (v.w - mn.w) * rq.w * gg.w + bb.w;
            v.x = v.x / (1.f + __expf(-v.x));
            v.y = v.y / (1.f + __expf(-v.y));
            v.z = v.z / (1.f + __expf(-v.z));
            v.w = v.w / (1.f + __expf(-v.w));
        }
        *(float4*)&sr[i] = v;
    }
    __syncthreads();
    int js = (tid & 15) * 4;
    int r  = tid >> 4;
    float acc[4][4];
#pragma unroll
    for (int i = 0; i < 4; ++i) { acc[i][0]=0.f; acc[i][1]=0.f; acc[i][2]=0.f; acc[i][3]=0.f; }
#pragma unroll 4
    for (int k = 0; k < COUT; ++k) {
        float4 w = *(float4*)&sW[k * COUT + js];
#pragma unroll
        for (int i = 0; i < 4; ++i) {
            float a = sr[(r * 4 + i) * COUT + k];
            acc[i][0] = fmaf(a, w.x, acc[i][0]);
            acc[i][1] = fmaf(a, w.y, acc[i][1]);
            acc[i][2] = fmaf(a, w.z, acc[i][2]);
            acc[i][3] = fmaf(a, w.w, acc[i][3]);
        }
    }
    float s1[4] = {0,0,0,0}, s2[4] = {0,0,0,0};
#pragma unroll
    for (int i = 0; i < 4; ++i) {
        int node = nbase + r * 4 + i;
        if (node < N_NODES) {
            *(float4*)&t3[(long)node * COUT + js] =
                make_float4(acc[i][0], acc[i][1], acc[i][2], acc[i][3]);
#pragma unroll
            for (int jj = 0; jj < 4; ++jj) {
                s1[jj] += acc[i][jj];
                s2[jj] += acc[i][jj] * acc[i][jj];
            }
        }
    }
    float* p = P + (long)blockIdx.x * 2048 + r * 128;
    *(float4*)&p[js]      = make_float4(s1[0], s1[1], s1[2], s1[3]);
    *(float4*)&p[64 + js] = make_float4(s2[0], s2[1], s2[2], s2[3]);
}

// ---------------- final: out = silu(BN3(t3)) --------------------------------
__global__ void final_kernel(const float* __restrict__ t3, const float* __restrict__ mr3,
                             const float* __restrict__ g, const float* __restrict__ be,
                             float* __restrict__ out) {
    long i = (long)blockIdx.x * blockDim.x + threadIdx.x;
    int j = (int)(i & 63);
    float v = t3[i];
    v = (v - mr3[j]) * mr3[COUT + j] * g[j] + be[j];
    out[i] = v / (1.f + __expf(-v));
}

extern "C" void kernel_launch(void* const* d_in, const int* in_sizes, int n_in,
                              void* d_out, int out_size, void* d_ws, size_t ws_size,
                              hipStream_t stream) {
    const float* x   = (const float*)d_in[0];
    const int*   ei  = (const int*)d_in[1];
    const float* ea  = (const float*)d_in[2];
    const float* W1  = (const float*)d_in[4];
    const float* b1  = (const float*)d_in[5];
    const float* gm  = (const float*)d_in[6];
    const float* bm  = (const float*)d_in[7];
    const float* W2  = (const float*)d_in[8];
    const float* b2  = (const float*)d_in[9];
    const float* g1  = (const float*)d_in[10];
    const float* be1 = (const float*)d_in[11];
    const float* Wl  = (const float*)d_in[12];
    const float* g2  = (const float*)d_in[13];
    const float* be2 = (const float*)d_in[14];
    float* out = (float*)d_out;

    // workspace: h0[N*64] | t1[N*128] | h2[N*64] | Sfin[512]
    // stat partials alias dead regions: P1->h2, P2->h0, P3->t1
    // sort arrays (es int2[E], cnt, offs, cursor, chunkS) live in t1 region
    float* h0 = (float*)d_ws;
    float* t1 = h0 + (long)N_NODES * CIN;
    float* h2 = t1 + (long)N_NODES * CHID;
    float* t3 = h0;
    float* Sfin = h2 + (long)N_NODES * COUT;
    float* P1 = h2;
    float* P2 = h0;
    float* P3 = t1;
    int2* es    = (int2*)t1;
    int* cnt    = (int*)(es + E_EDGES);
    int* offs   = cnt + N_NODES;
    int* cursor = offs + N_NODES;
    int* chunkS = cursor + N_NODES;

    const int nchunks = (N_NODES + SCAN_CHUNK - 1) / SCAN_CHUNK;
    const float invN = 1.f / N_NODES;

    hipMemsetAsync(cnt, 0, (size_t)N_NODES * sizeof(int), stream);

    hist_kernel<<<(E_EDGES + 255) / 256, 256, 0, stream>>>(ei, cnt);
    scan1_kernel<<<nchunks, 256, 0, stream>>>(cnt, offs, chunkS);
    scan2_kernel<<<1, 256, 0, stream>>>(chunkS, nchunks);
    scan3_kernel<<<(N_NODES + 255) / 256, 256, 0, stream>>>(offs, chunkS, cursor);
    scatter_kernel<<<(E_EDGES + 255) / 256, 256, 0, stream>>>(ei, cursor, es);
    gather_kernel<<<(N_NODES * 64 + 255) / 256, 256, 0, stream>>>(x, ea, es, offs, cnt, h0);

    gemm1_kernel<<<NB, 256, 0, stream>>>(h0, W1, b1, t1, P1);
    reduce_kernel<<<CHID, 256, 0, stream>>>(P1, NB * 8, CHID, Sfin, invN);
    gemm2_kernel<<<NB, 256, 0, stream>>>(t1, Sfin, gm, bm, W2, b2, h2, P2);
    reduce_kernel<<<COUT, 256, 0, stream>>>(P2, NB * 16, COUT, Sfin + 256, invN);
    gemm3_kernel<<<NB, 256, 0, stream>>>(h2, Sfin + 256, g1, be1, Wl, t3, P3);
    reduce_kernel<<<COUT, 256, 0, stream>>>(P3, NB * 16, COUT, Sfin + 384, invN);
    final_kernel<<<(N_NODES * COUT) / 256, 256, 0, stream>>>(t3, Sfin + 384, g2, be2, out);
}